// Round 5
// baseline (41.015 us; speedup 1.0000x reference)
//
#include <hip/hip_runtime.h>

#define FAPE_EPS   1e-4f
#define FAPE_CLAMP 10.0f
#define FAPE_Z     10.0f

constexpr int TPB   = 256;        // threads per block
constexpr int FPB   = 8;          // frames per block
constexpr int APT   = 4;          // atoms per thread
constexpr int ATILE = TPB * APT;  // 1024 atoms per block tile

// Arrival ticket for the last-block-done pattern. Module-scope device global:
// zero at load time, and the finalizing block resets it to 0 at the end of
// EVERY call, so each kernel_launch performs identical work on identical
// state (deterministic; nothing is skipped or cached across calls).
__device__ unsigned g_ticket = 0;

// Block reduce; result valid on tid==0. Self-contained (trailing sync so
// swave can be reused immediately).
__device__ __forceinline__ float blockReduce(float v, float* swave, int tid) {
    for (int off = 32; off > 0; off >>= 1) v += __shfl_down(v, off);
    if ((tid & 63) == 0) swave[tid >> 6] = v;
    __syncthreads();
    float s = 0.f;
    if (tid == 0) {
#pragma unroll
        for (int w = 0; w < TPB / 64; ++w) s += swave[w];
    }
    __syncthreads();
    return s;
}

// Single fused kernel. Block = (batch, frame-tile, atom-tile).
//  - atoms loaded once per thread as float4s into registers, reused across
//    FPB frames (frame data read block-uniformly -> scalar/L1-broadcast path)
//  - per-block partial -> dedicated ws slot (written before read every call,
//    so the 0xAA poison is harmless; no init node needed)
//  - ftile==0 blocks also write per-atom-tile mask partials
//  - threadfence + device-scope ticket; last arriving block reduces all
//    partials (agent-scope atomic loads, L1-proof), writes out, resets ticket
__global__ __launch_bounds__(TPB) void fape_fused_kernel(
        const float* __restrict__ Rp, const float* __restrict__ tp,
        const float* __restrict__ pp, const float* __restrict__ mask,
        const float* __restrict__ Rt, const float* __restrict__ tt,
        const float* __restrict__ pt, float* __restrict__ out,
        float* __restrict__ ws, int N, int A,
        int fTilesPerBatch, int atomTiles, int b, unsigned nBlocks) {

    const int tid   = threadIdx.x;
    const int t     = blockIdx.x;
    const int atile = t % atomTiles;
    const int ft    = t / atomTiles;
    const int batch = ft / fTilesPerBatch;
    const int ftile = ft % fTilesPerBatch;
    const int f0    = ftile * FPB;
    const int P     = fTilesPerBatch * atomTiles;   // partials per batch

    float* __restrict__ partial  = ws;                       // [nBlocks]
    float* __restrict__ maskPart = ws + nBlocks;             // [b * atomTiles]

    const float* __restrict__ ppb = pp   + (size_t)batch * A * 3;
    const float* __restrict__ ptb = pt   + (size_t)batch * A * 3;
    const float* __restrict__ mb  = mask + (size_t)batch * A;

    // ---- load APT atoms into registers (7 x float4) ----
    float p[APT][3], q[APT][3], m[APT];
    const int j0 = atile * ATILE + tid * APT;
    if (j0 + APT <= A) {
        const float4* p4 = reinterpret_cast<const float4*>(ppb + (size_t)j0 * 3);
        const float4* q4 = reinterpret_cast<const float4*>(ptb + (size_t)j0 * 3);
        const float4  P0 = p4[0], P1 = p4[1], P2 = p4[2];
        const float4  Q0 = q4[0], Q1 = q4[1], Q2 = q4[2];
        const float4  M  = *reinterpret_cast<const float4*>(mb + j0);
        p[0][0]=P0.x; p[0][1]=P0.y; p[0][2]=P0.z;
        p[1][0]=P0.w; p[1][1]=P1.x; p[1][2]=P1.y;
        p[2][0]=P1.z; p[2][1]=P1.w; p[2][2]=P2.x;
        p[3][0]=P2.y; p[3][1]=P2.z; p[3][2]=P2.w;
        q[0][0]=Q0.x; q[0][1]=Q0.y; q[0][2]=Q0.z;
        q[1][0]=Q0.w; q[1][1]=Q1.x; q[1][2]=Q1.y;
        q[2][0]=Q1.z; q[2][1]=Q1.w; q[2][2]=Q2.x;
        q[3][0]=Q2.y; q[3][1]=Q2.z; q[3][2]=Q2.w;
        m[0]=M.x; m[1]=M.y; m[2]=M.z; m[3]=M.w;
    } else {
#pragma unroll
        for (int k = 0; k < APT; ++k) {
            const int j = j0 + k;
            if (j < A) {
                p[k][0]=ppb[j*3+0]; p[k][1]=ppb[j*3+1]; p[k][2]=ppb[j*3+2];
                q[k][0]=ptb[j*3+0]; q[k][1]=ptb[j*3+1]; q[k][2]=ptb[j*3+2];
                m[k]=mb[j];
            } else {
                p[k][0]=p[k][1]=p[k][2]=0.f;
                q[k][0]=q[k][1]=q[k][2]=0.f;
                m[k]=0.f;
            }
        }
    }

    float local = 0.0f;
#pragma unroll
    for (int f = 0; f < FPB; ++f) {
        const int fl = f0 + f;
        if (fl < N) {
            const size_t fi = (size_t)batch * N + fl;   // block-uniform
            const float* __restrict__ rp = Rp + fi * 9;
            const float* __restrict__ rt = Rt + fi * 9;
            const float* __restrict__ tv = tp + fi * 3;
            const float* __restrict__ uv = tt + fi * 3;

            const float rp00=rp[0], rp01=rp[1], rp02=rp[2];
            const float rp10=rp[3], rp11=rp[4], rp12=rp[5];
            const float rp20=rp[6], rp21=rp[7], rp22=rp[8];
            const float rt00=rt[0], rt01=rt[1], rt02=rt[2];
            const float rt10=rt[3], rt11=rt[4], rt12=rt[5];
            const float rt20=rt[6], rt21=rt[7], rt22=rt[8];
            const float tp0=tv[0], tp1=tv[1], tp2=tv[2];
            const float tt0=uv[0], tt1=uv[1], tt2=uv[2];

            // c = Rt^T t_t - Rp^T t_p
            const float c0 = rt00*tt0 + rt10*tt1 + rt20*tt2 - (rp00*tp0 + rp10*tp1 + rp20*tp2);
            const float c1 = rt01*tt0 + rt11*tt1 + rt21*tt2 - (rp01*tp0 + rp11*tp1 + rp21*tp2);
            const float c2 = rt02*tt0 + rt12*tt1 + rt22*tt2 - (rp02*tp0 + rp12*tp1 + rp22*tp2);

#pragma unroll
            for (int k = 0; k < APT; ++k) {
                float x0 = c0 + rp00*p[k][0] + rp10*p[k][1] + rp20*p[k][2]
                              - rt00*q[k][0] - rt10*q[k][1] - rt20*q[k][2];
                float x1 = c1 + rp01*p[k][0] + rp11*p[k][1] + rp21*p[k][2]
                              - rt01*q[k][0] - rt11*q[k][1] - rt21*q[k][2];
                float x2 = c2 + rp02*p[k][0] + rp12*p[k][1] + rp22*p[k][2]
                              - rt02*q[k][0] - rt12*q[k][1] - rt22*q[k][2];
                const float d = __builtin_amdgcn_sqrtf(x0*x0 + x1*x1 + x2*x2 + FAPE_EPS);
                local += fminf(d, FAPE_CLAMP) * m[k];
            }
        }
    }

    __shared__ float swave[TPB / 64];
    __shared__ bool  sLast;

    const float bs = blockReduce(local, swave, tid);
    if (tid == 0) partial[t] = bs;

    if (ftile == 0) {   // block-uniform branch
        const float mbs = blockReduce(m[0] + m[1] + m[2] + m[3], swave, tid);
        if (tid == 0) maskPart[batch * atomTiles + atile] = mbs;
    }

    // ---- arrival ticket ----
    if (tid == 0) {
        __threadfence();   // make this block's partials visible device-wide
        const unsigned old = __hip_atomic_fetch_add(&g_ticket, 1u,
                                  __ATOMIC_ACQ_REL, __HIP_MEMORY_SCOPE_AGENT);
        sLast = (old == nBlocks - 1u);
    }
    __syncthreads();
    if (!sLast) return;

    // ---- last block: finalize ----
    __threadfence();   // acquire side for all threads of this block
    for (int bb = 0; bb < b; ++bb) {
        float s = 0.f;
        for (int i = tid; i < P; i += TPB)
            s += __hip_atomic_load(&partial[bb * P + i],
                                   __ATOMIC_RELAXED, __HIP_MEMORY_SCOPE_AGENT);
        const float sb = blockReduce(s, swave, tid);

        float mv = 0.f;
        if (tid < atomTiles)
            mv = __hip_atomic_load(&maskPart[bb * atomTiles + tid],
                                   __ATOMIC_RELAXED, __HIP_MEMORY_SCOPE_AGENT);
        const float msb = blockReduce(mv, swave, tid);

        if (tid == 0)
            out[bb] = sb / (fmaxf(msb, 1.0f) * (float)N * FAPE_Z);
    }

    if (tid == 0)   // restore the ticket's invariant state for the next call
        __hip_atomic_store(&g_ticket, 0u, __ATOMIC_RELEASE, __HIP_MEMORY_SCOPE_AGENT);
}

extern "C" void kernel_launch(void* const* d_in, const int* in_sizes, int n_in,
                              void* d_out, int out_size, void* d_ws, size_t ws_size,
                              hipStream_t stream) {
    const float* Rp   = (const float*)d_in[0];  // [b,N,3,3]
    const float* tp   = (const float*)d_in[1];  // [b,N,3]
    const float* pp   = (const float*)d_in[2];  // [b,N,14,3]
    const float* mask = (const float*)d_in[3];  // [b,N,14]
    const float* Rt   = (const float*)d_in[4];
    const float* tt   = (const float*)d_in[5];
    const float* pt   = (const float*)d_in[6];
    float* out = (float*)d_out;
    float* ws  = (float*)d_ws;

    const int b  = out_size;
    const int bN = in_sizes[1] / 3;
    const int N  = bN / b;
    const int A  = N * 14;

    const int fTilesPerBatch = (N + FPB - 1) / FPB;
    const int atomTiles      = (A + ATILE - 1) / ATILE;
    const unsigned nBlocks   = (unsigned)(b * fTilesPerBatch * atomTiles);

    fape_fused_kernel<<<dim3(nBlocks), dim3(TPB), 0, stream>>>(
        Rp, tp, pp, mask, Rt, tt, pt, out, ws,
        N, A, fTilesPerBatch, atomTiles, b, nBlocks);
}

// Round 6
// 21.362 us; speedup vs baseline: 1.9200x; 1.9200x over previous
//
#include <hip/hip_runtime.h>

#define FAPE_EPS   1e-4f
#define FAPE_CLAMP 10.0f
#define FAPE_Z     10.0f

constexpr int TPB   = 256;        // threads per block
constexpr int FPB   = 16;         // frames per block
constexpr int APT   = 4;          // atoms per thread
constexpr int ATILE = TPB * APT;  // 1024 atoms per block tile
constexpr int GRPSZ = 16;         // arrival-tree group size
constexpr int MAXB  = 16;         // max batch supported
constexpr int MAXG  = 1024;       // max arrival groups
constexpr double FX = 16777216.0; // 2^24 fixed-point scale

// Module-scope accumulators/tickets: zero at load, and the finalizing thread
// resets ALL touched entries to zero at the end of EVERY call, so each call
// sees identical state (deterministic; harness poison only covers d_out/d_ws).
// u64 integer atomics: native HW op, order-independent => bit-deterministic.
__device__ unsigned long long g_acc[MAXB]  = {};
__device__ unsigned long long g_msum[MAXB] = {};
__device__ unsigned           g_gt[MAXG]   = {};
__device__ unsigned           g_st         = 0;

__device__ __forceinline__ float blockReduce(float v, float* swave, int tid) {
    for (int off = 32; off > 0; off >>= 1) v += __shfl_down(v, off);
    if ((tid & 63) == 0) swave[tid >> 6] = v;
    __syncthreads();
    float s = 0.f;
    if (tid == 0) {
#pragma unroll
        for (int w = 0; w < TPB / 64; ++w) s += swave[w];
    }
    __syncthreads();
    return s;
}

// Single fused kernel, fence-free last-block-done:
//  - block = (batch, frame-tile, atom-tile); atoms loaded once as float4s
//    into registers, reused across FPB frames
//  - per-block partial -> ONE u64 fixed-point atomicAdd (device-coherent RMW,
//    no cache fence needed); ftile==0 blocks also add their mask partial
//  - s_waitcnt vmcnt(0) orders payload-add before ticket-add
//  - two-level arrival tree (GRPSZ-wide groups -> super ticket); the very
//    last arriver finalizes out[0..b) and zeroes all globals for next call
__global__ __launch_bounds__(TPB) void fape_fused_kernel(
        const float* __restrict__ Rp, const float* __restrict__ tp,
        const float* __restrict__ pp, const float* __restrict__ mask,
        const float* __restrict__ Rt, const float* __restrict__ tt,
        const float* __restrict__ pt, float* __restrict__ out,
        int N, int A, int fTilesPerBatch, int atomTiles, int b,
        unsigned nBlocks, unsigned nGroups) {

    const int tid   = threadIdx.x;
    const int t     = blockIdx.x;
    const int atile = t % atomTiles;
    const int ft    = t / atomTiles;
    const int batch = ft / fTilesPerBatch;
    const int ftile = ft % fTilesPerBatch;
    const int f0    = ftile * FPB;

    const float* __restrict__ ppb = pp   + (size_t)batch * A * 3;
    const float* __restrict__ ptb = pt   + (size_t)batch * A * 3;
    const float* __restrict__ mb  = mask + (size_t)batch * A;

    // ---- load APT atoms into registers (7 x float4) ----
    float p[APT][3], q[APT][3], m[APT];
    const int j0 = atile * ATILE + tid * APT;
    if (j0 + APT <= A) {
        const float4* p4 = reinterpret_cast<const float4*>(ppb + (size_t)j0 * 3);
        const float4* q4 = reinterpret_cast<const float4*>(ptb + (size_t)j0 * 3);
        const float4  P0 = p4[0], P1 = p4[1], P2 = p4[2];
        const float4  Q0 = q4[0], Q1 = q4[1], Q2 = q4[2];
        const float4  M  = *reinterpret_cast<const float4*>(mb + j0);
        p[0][0]=P0.x; p[0][1]=P0.y; p[0][2]=P0.z;
        p[1][0]=P0.w; p[1][1]=P1.x; p[1][2]=P1.y;
        p[2][0]=P1.z; p[2][1]=P1.w; p[2][2]=P2.x;
        p[3][0]=P2.y; p[3][1]=P2.z; p[3][2]=P2.w;
        q[0][0]=Q0.x; q[0][1]=Q0.y; q[0][2]=Q0.z;
        q[1][0]=Q0.w; q[1][1]=Q1.x; q[1][2]=Q1.y;
        q[2][0]=Q1.z; q[2][1]=Q1.w; q[2][2]=Q2.x;
        q[3][0]=Q2.y; q[3][1]=Q2.z; q[3][2]=Q2.w;
        m[0]=M.x; m[1]=M.y; m[2]=M.z; m[3]=M.w;
    } else {
#pragma unroll
        for (int k = 0; k < APT; ++k) {
            const int j = j0 + k;
            if (j < A) {
                p[k][0]=ppb[j*3+0]; p[k][1]=ppb[j*3+1]; p[k][2]=ppb[j*3+2];
                q[k][0]=ptb[j*3+0]; q[k][1]=ptb[j*3+1]; q[k][2]=ptb[j*3+2];
                m[k]=mb[j];
            } else {
                p[k][0]=p[k][1]=p[k][2]=0.f;
                q[k][0]=q[k][1]=q[k][2]=0.f;
                m[k]=0.f;
            }
        }
    }

    float local = 0.0f;
    for (int f = 0; f < FPB; ++f) {
        const int fl = f0 + f;
        if (fl < N) {
            const size_t fi = (size_t)batch * N + fl;   // block-uniform
            const float* __restrict__ rp = Rp + fi * 9;
            const float* __restrict__ rt = Rt + fi * 9;
            const float* __restrict__ tv = tp + fi * 3;
            const float* __restrict__ uv = tt + fi * 3;

            const float rp00=rp[0], rp01=rp[1], rp02=rp[2];
            const float rp10=rp[3], rp11=rp[4], rp12=rp[5];
            const float rp20=rp[6], rp21=rp[7], rp22=rp[8];
            const float rt00=rt[0], rt01=rt[1], rt02=rt[2];
            const float rt10=rt[3], rt11=rt[4], rt12=rt[5];
            const float rt20=rt[6], rt21=rt[7], rt22=rt[8];
            const float tp0=tv[0], tp1=tv[1], tp2=tv[2];
            const float tt0=uv[0], tt1=uv[1], tt2=uv[2];

            // c = Rt^T t_t - Rp^T t_p
            const float c0 = rt00*tt0 + rt10*tt1 + rt20*tt2 - (rp00*tp0 + rp10*tp1 + rp20*tp2);
            const float c1 = rt01*tt0 + rt11*tt1 + rt21*tt2 - (rp01*tp0 + rp11*tp1 + rp21*tp2);
            const float c2 = rt02*tt0 + rt12*tt1 + rt22*tt2 - (rp02*tp0 + rp12*tp1 + rp22*tp2);

#pragma unroll
            for (int k = 0; k < APT; ++k) {
                float x0 = c0 + rp00*p[k][0] + rp10*p[k][1] + rp20*p[k][2]
                              - rt00*q[k][0] - rt10*q[k][1] - rt20*q[k][2];
                float x1 = c1 + rp01*p[k][0] + rp11*p[k][1] + rp21*p[k][2]
                              - rt01*q[k][0] - rt11*q[k][1] - rt21*q[k][2];
                float x2 = c2 + rp02*p[k][0] + rp12*p[k][1] + rp22*p[k][2]
                              - rt02*q[k][0] - rt12*q[k][1] - rt22*q[k][2];
                const float d = __builtin_amdgcn_sqrtf(x0*x0 + x1*x1 + x2*x2 + FAPE_EPS);
                local += fminf(d, FAPE_CLAMP) * m[k];
            }
        }
    }

    __shared__ float swave[TPB / 64];
    const float bs = blockReduce(local, swave, tid);

    float mbs = 0.f;
    if (ftile == 0)   // block-uniform branch
        mbs = blockReduce(m[0] + m[1] + m[2] + m[3], swave, tid);

    if (tid != 0) return;

    // ---- payload: device-coherent integer RMWs (no fence needed) ----
    __hip_atomic_fetch_add(&g_acc[batch],
        (unsigned long long)((double)bs * FX + 0.5),
        __ATOMIC_RELAXED, __HIP_MEMORY_SCOPE_AGENT);
    if (ftile == 0)
        __hip_atomic_fetch_add(&g_msum[batch],
            (unsigned long long)((double)mbs * FX + 0.5),
            __ATOMIC_RELAXED, __HIP_MEMORY_SCOPE_AGENT);

    // order payload-adds before the ticket-add (drain to coherency point)
    asm volatile("s_waitcnt vmcnt(0)" ::: "memory");

    // ---- arrival tree ----
    const unsigned g     = (unsigned)t / GRPSZ;
    const unsigned gbase = g * GRPSZ;
    const unsigned gsz   = (nBlocks - gbase < (unsigned)GRPSZ) ? (nBlocks - gbase)
                                                               : (unsigned)GRPSZ;
    const unsigned old = __hip_atomic_fetch_add(&g_gt[g], 1u,
                              __ATOMIC_RELAXED, __HIP_MEMORY_SCOPE_AGENT);
    if (old != gsz - 1u) return;   // not group-last

    const unsigned old2 = __hip_atomic_fetch_add(&g_st, 1u,
                               __ATOMIC_RELAXED, __HIP_MEMORY_SCOPE_AGENT);
    if (old2 != nGroups - 1u) return;  // not global-last

    // ---- global-last thread: finalize + reset state for next call ----
    for (int bb = 0; bb < b; ++bb) {
        const unsigned long long av =
            __hip_atomic_load(&g_acc[bb],  __ATOMIC_RELAXED, __HIP_MEMORY_SCOPE_AGENT);
        const unsigned long long mv =
            __hip_atomic_load(&g_msum[bb], __ATOMIC_RELAXED, __HIP_MEMORY_SCOPE_AGENT);
        const double s  = (double)av / FX;
        const double ms = (double)mv / FX;
        out[bb] = (float)(s / (fmax(ms, 1.0) * (double)N * (double)FAPE_Z));
        __hip_atomic_store(&g_acc[bb],  0ull, __ATOMIC_RELAXED, __HIP_MEMORY_SCOPE_AGENT);
        __hip_atomic_store(&g_msum[bb], 0ull, __ATOMIC_RELAXED, __HIP_MEMORY_SCOPE_AGENT);
    }
    for (unsigned i = 0; i < nGroups; ++i)
        __hip_atomic_store(&g_gt[i], 0u, __ATOMIC_RELAXED, __HIP_MEMORY_SCOPE_AGENT);
    __hip_atomic_store(&g_st, 0u, __ATOMIC_RELAXED, __HIP_MEMORY_SCOPE_AGENT);
}

extern "C" void kernel_launch(void* const* d_in, const int* in_sizes, int n_in,
                              void* d_out, int out_size, void* d_ws, size_t ws_size,
                              hipStream_t stream) {
    const float* Rp   = (const float*)d_in[0];  // [b,N,3,3]
    const float* tp   = (const float*)d_in[1];  // [b,N,3]
    const float* pp   = (const float*)d_in[2];  // [b,N,14,3]
    const float* mask = (const float*)d_in[3];  // [b,N,14]
    const float* Rt   = (const float*)d_in[4];
    const float* tt   = (const float*)d_in[5];
    const float* pt   = (const float*)d_in[6];
    float* out = (float*)d_out;

    const int b  = out_size;
    const int bN = in_sizes[1] / 3;
    const int N  = bN / b;
    const int A  = N * 14;

    const int fTilesPerBatch = (N + FPB - 1) / FPB;
    const int atomTiles      = (A + ATILE - 1) / ATILE;
    const unsigned nBlocks   = (unsigned)(b * fTilesPerBatch * atomTiles);
    const unsigned nGroups   = (nBlocks + GRPSZ - 1) / GRPSZ;

    fape_fused_kernel<<<dim3(nBlocks), dim3(TPB), 0, stream>>>(
        Rp, tp, pp, mask, Rt, tt, pt, out,
        N, A, fTilesPerBatch, atomTiles, b, nBlocks, nGroups);
}